// Round 14
// baseline (112.226 us; speedup 1.0000x reference)
//
#include <hip/hip_runtime.h>

typedef __bf16 bf16;
typedef __bf16 bf16x8 __attribute__((ext_vector_type(8)));
typedef __bf16 bf16x4 __attribute__((ext_vector_type(4)));
typedef float f32x4 __attribute__((ext_vector_type(4)));
typedef unsigned int u32;

#define NB    2048
#define NM    26
#define NJP   27      // 26 K-chunks + 1 pad (layout constant; pad never read now)

__device__ __forceinline__ void gl_lds16(const bf16* g, bf16* l) {
  __builtin_amdgcn_global_load_lds(
      (const __attribute__((address_space(1))) void*)g,
      (__attribute__((address_space(3))) void*)l, 16, 0, 0);
}

__device__ __forceinline__ bf16x8 splat8(u32 p) {
  union { u32 u[4]; bf16x8 v; } s;
  s.u[0] = p; s.u[1] = p; s.u[2] = p; s.u[3] = p;
  return s.v;
}

__device__ __forceinline__ u32 dup16(float v) {
  union { bf16 h; unsigned short s; } cv; cv.h = (bf16)v;
  return (u32)cv.s * 0x10001u;
}

// ---------------- prep: frag-linear weight tiles ------------------------------
// FRAGMENT-LINEAR 64x32 tile: element (r=ni*16+lr, c=lq*8+el) at
// ni*512 + lq*128 + lr*8 + el.
__global__ __launch_bounds__(256) void prep_all(
    const float* __restrict__ W1, const float* __restrict__ W2,
    bf16* __restrict__ w1t, bf16* __restrict__ w2t2)
{
  const int bid = blockIdx.x, t = threadIdx.x;
  if (bid < 432) {                        // w1t tiles [cs(2)][c(NJP)], frag-linear
    int e = bid*256 + t;
    int el = e & 7, lr = (e >> 3) & 15, lq = (e >> 7) & 3, ni = (e >> 9) & 3;
    int rest = e >> 11;
    int c = rest % NJP, cs_idx = rest / NJP;
    int h = cs_idx*64 + ni*16 + lr;
    int i = lq*8 + el;
    float v = (i < NM && c < NM) ? W1[h*(NM*NM) + i*NM + c] : 0.f;
    w1t[e] = (bf16)v;
  } else {                                // w2t2 tiles [cs(2)][kc(130)], frag-linear
    int e = (bid-432)*256 + t;            // flatK = kc*32 + c  (kc=i, c=j)
    int el = e & 7, lr = (e >> 3) & 15, lq = (e >> 7) & 3, ni = (e >> 9) & 3;
    int rest = e >> 11;                   // [0, 260)
    int kc = rest % 130, cs_idx = rest / 130;
    int h = cs_idx*64 + ni*16 + lr;
    int c = lq*8 + el;
    float v = (kc < 128 && c < NM) ? W2[h*(128*NM) + kc*NM + c] : 0.f;
    w2t2[e] = (bf16)v;
  }
}

// one K-PAIR step: barrier; stage chunk-pair P+1 (8 KB) into LDS buf NXT;
// prefetch 4 A-scalars; compute both chunks of pair P from buf CUR (16 MFMA).
// Halves barrier count vs one-chunk STEP — the barrier vmcnt-drain was the
// dominant stall (R13 analysis: ~600cy/STEP wall vs ~150cy issued work).
#define PAIR(CUR, NXT, P) do {                                                 \
  __syncthreads();                                                             \
  gl_lds16(tb + (long)((P)+1)*4096 + t*8,        &ldsB[NXT][t*8]);             \
  gl_lds16(tb + (long)((P)+1)*4096 + 2048 + t*8, &ldsB[NXT][2048 + t*8]);      \
  sc[NXT][0] = dup16(spw[(2*(P)+2)*32]);                                       \
  sc[NXT][1] = dup16(spw[(2*(P)+2)*32 + 16]);                                  \
  sc[NXT][2] = dup16(spw[(2*(P)+3)*32]);                                       \
  sc[NXT][3] = dup16(spw[(2*(P)+3)*32 + 16]);                                  \
  bf16x8 bfr[4];                                                               \
  _Pragma("unroll")                                                            \
  for (int ni = 0; ni < 4; ++ni)                                               \
    bfr[ni] = *(const bf16x8*)&ldsB[CUR][ni*512 + fo];                         \
  _Pragma("unroll")                                                            \
  for (int mi = 0; mi < 2; ++mi) {                                             \
    bf16x8 af = xf[mi] * splat8(sc[CUR][mi]);                                  \
    _Pragma("unroll")                                                          \
    for (int ni = 0; ni < 4; ++ni)                                             \
      acc[mi][ni] = __builtin_amdgcn_mfma_f32_16x16x32_bf16(af, bfr[ni],       \
                                                            acc[mi][ni], 0, 0, 0); \
  }                                                                            \
  _Pragma("unroll")                                                            \
  for (int ni = 0; ni < 4; ++ni)                                               \
    bfr[ni] = *(const bf16x8*)&ldsB[CUR][2048 + ni*512 + fo];                  \
  _Pragma("unroll")                                                            \
  for (int mi = 0; mi < 2; ++mi) {                                             \
    bf16x8 af = xf[mi] * splat8(sc[CUR][2 + mi]);                              \
    _Pragma("unroll")                                                          \
    for (int ni = 0; ni < 4; ++ni)                                             \
      acc[mi][ni] = __builtin_amdgcn_mfma_f32_16x16x32_bf16(af, bfr[ni],       \
                                                            acc[mi][ni], 0, 0, 0); \
  }                                                                            \
} while (0)

// ---------------- layer 1 + fused G: wave = 1 batch (32 rows) x one cs-half ---
// NOTE: __launch_bounds__(256, 4) is load-bearing. 5/6 waves/EU makes the
// allocator collapse to 40 VGPRs -> acc spills -> ~90 MB scratch traffic
// (measured R7, R12). Do not raise.
__global__ __launch_bounds__(256, 4) void cin1G(
    const float* __restrict__ in, const bf16* __restrict__ w1t,
    const float* __restrict__ b1, const float* __restrict__ b2,
    bf16* __restrict__ G2, float* __restrict__ out)
{
  __shared__ __align__(16) bf16 ldsB[2][4096];    // double buffer of chunk-PAIRS
  __shared__ __align__(16) bf16 ldsT[4][64*36];   // wave-private x1^T [i64][k32+pad]
  const int t = threadIdx.x;
  const int lane = t & 63, w = t >> 6;
  const int cs_idx = blockIdx.x & 1, cs = cs_idx * 64;
  const int strip = blockIdx.x >> 1;
  const int bw = strip*4 + w;                     // this wave's batch
  const int lr = lane & 15, lq = lane >> 4;
  const int fo = lq*128 + lr*8;

  const float* bin = in + (long)bw*(NM*32);
  const float* spw = bin + lr;                    // + j*32 (+16 for k-high)

  // out2-half bias init (gemm2 atomics come after this kernel completes)
  out[bw*256 + 128 + cs + lane] = 32.0f * b2[cs + lane];

  // x0 A-frags direct from in: xf[mi][e] = x0[bw][j=lq*8+e][k=mi*16+lr]
  bf16x8 xf[2];
  #pragma unroll
  for (int mi = 0; mi < 2; ++mi)
    #pragma unroll
    for (int e = 0; e < 8; ++e) {
      int j = lq*8 + e;
      xf[mi][e] = (bf16)((j < NM) ? bin[j*32 + mi*16 + lr] : 0.f);
    }

  f32x4 acc[2][4];
  #pragma unroll
  for (int mi=0; mi<2; ++mi)
    #pragma unroll
    for (int ni=0; ni<4; ++ni) acc[mi][ni] = {0.f,0.f,0.f,0.f};

  const bf16* tb = w1t + (long)cs_idx*NJP*2048;

  u32 sc[2][4];
  gl_lds16(tb + t*8,        &ldsB[0][t*8]);       // stage pair 0 (chunks 0,1)
  gl_lds16(tb + 2048 + t*8, &ldsB[0][2048 + t*8]);
  sc[0][0] = dup16(spw[0]);   sc[0][1] = dup16(spw[16]);
  sc[0][2] = dup16(spw[32]);  sc[0][3] = dup16(spw[48]);

  for (int jj = 0; jj < 6; ++jj) {                // pairs 0..11
    PAIR(0, 1, 2*jj);
    PAIR(1, 0, 2*jj + 1);
  }
  // final pair 12 (chunks 24,25) from buf 0, no staging
  {
    __syncthreads();
    bf16x8 bfr[4];
    #pragma unroll
    for (int ni = 0; ni < 4; ++ni)
      bfr[ni] = *(const bf16x8*)&ldsB[0][ni*512 + fo];
    #pragma unroll
    for (int mi = 0; mi < 2; ++mi) {
      bf16x8 af = xf[mi] * splat8(sc[0][mi]);
      #pragma unroll
      for (int ni = 0; ni < 4; ++ni)
        acc[mi][ni] = __builtin_amdgcn_mfma_f32_16x16x32_bf16(af, bfr[ni], acc[mi][ni], 0, 0, 0);
    }
    #pragma unroll
    for (int ni = 0; ni < 4; ++ni)
      bfr[ni] = *(const bf16x8*)&ldsB[0][2048 + ni*512 + fo];
    #pragma unroll
    for (int mi = 0; mi < 2; ++mi) {
      bf16x8 af = xf[mi] * splat8(sc[0][2 + mi]);
      #pragma unroll
      for (int ni = 0; ni < 4; ++ni)
        acc[mi][ni] = __builtin_amdgcn_mfma_f32_16x16x32_bf16(af, bfr[ni], acc[mi][ni], 0, 0, 0);
    }
  }

  float bias[4];
  #pragma unroll
  for (int ni=0; ni<4; ++ni) bias[ni] = b1[cs + ni*16 + lr];

  // out[bw][0:128] = k-sum of x1 + 32*bias
  #pragma unroll
  for (int ni=0; ni<4; ++ni) {
    float v = 0.f;
    #pragma unroll
    for (int mi=0; mi<2; ++mi)
      #pragma unroll
      for (int r=0; r<4; ++r) v += acc[mi][ni][r];
    v += __shfl_xor(v, 16, 64);
    v += __shfl_xor(v, 32, 64);
    if (lq == 0) out[bw*256 + cs + ni*16 + lr] = v + 32.0f * bias[ni];
  }

  // x1 (C-layout) -> wave-private LDS [i_local][k], row stride 36
  bf16* T = &ldsT[w][0];
  #pragma unroll
  for (int mi=0; mi<2; ++mi)
    #pragma unroll
    for (int ni=0; ni<4; ++ni) {
      bf16x4 pk;
      #pragma unroll
      for (int r=0; r<4; ++r) pk[r] = (bf16)(acc[mi][ni][r] + bias[ni]);
      *(bf16x4*)&T[(ni*16+lr)*36 + mi*16 + lq*4] = pk;
    }
  // no barrier: each wave reads only its own tile (lgkmcnt ordering)

  // B-frags: x0[j][k] from in
  bf16x8 bg[2];
  #pragma unroll
  for (int nt = 0; nt < 2; ++nt) {
    int j = nt*16 + lr;
    bf16x8 v;
    #pragma unroll
    for (int e=0; e<8; ++e) v[e] = (bf16)0.f;
    if (j < NM) {
      const float* src = bin + j*32 + lq*8;
      f32x4 a = *(const f32x4*)src, c = *(const f32x4*)(src+4);
      #pragma unroll
      for (int e=0; e<4; ++e) { v[e] = (bf16)a[e]; v[4+e] = (bf16)c[e]; }
    }
    bg[nt] = v;
  }
  // G-MFMAs + tiled G2 stores
  const long gbase = (long)(bw >> 5)*131072 + (bw & 31)*8;
  #pragma unroll
  for (int mt = 0; mt < 4; ++mt) {
    bf16x8 ag = *(const bf16x8*)&T[(mt*16+lr)*36 + lq*8];
    #pragma unroll
    for (int nt = 0; nt < 2; ++nt) {
      f32x4 z = {0.f,0.f,0.f,0.f};
      f32x4 g = __builtin_amdgcn_mfma_f32_16x16x32_bf16(ag, bg[nt], z, 0, 0, 0);
      const int jh = nt*2 + (lr >> 3), jl = lr & 7;
      #pragma unroll
      for (int r = 0; r < 4; ++r) {
        int i = cs + mt*16 + lq*4 + r;
        G2[gbase + (long)(i*4 + jh)*256 + jl] = (bf16)g[r];
      }
    }
  }
}

// ---------------- gemm2: out[b][128+h] += sum_K G[b][K]*W2p[h][K] -------------
// M=2048 b (tiles of 32), N=128 h, K=4096 flat; split-K x16; atomics into out.
#define STEPG(CUR, NXT, KN) do {                                               \
  _Pragma("unroll")                                                            \
  for (int mi = 0; mi < 2; ++mi)                                               \
    A[NXT][mi] = *(const bf16x8*)(Ab + (long)(KN)*1024 + mi*128);              \
  _Pragma("unroll")                                                            \
  for (int ni = 0; ni < 4; ++ni)                                               \
    B[NXT][ni] = *(const bf16x8*)(tb + (long)(KN)*2048 + ni*512);              \
  _Pragma("unroll")                                                            \
  for (int mi = 0; mi < 2; ++mi)                                               \
    _Pragma("unroll")                                                          \
    for (int ni = 0; ni < 4; ++ni)                                             \
      acc[mi][ni] = __builtin_amdgcn_mfma_f32_16x16x32_bf16(A[CUR][mi],        \
                                  B[CUR][ni], acc[mi][ni], 0, 0, 0);           \
} while (0)

__global__ __launch_bounds__(256, 4) void gemm2(
    const bf16* __restrict__ G2, const bf16* __restrict__ w2t2, float* __restrict__ out)
{
  const int t = threadIdx.x;
  const int lane = t & 63, w = t >> 6;
  const int s = blockIdx.x >> 5;              // 16 splits
  const int q32 = blockIdx.x & 31;
  const int tile = q32*4 + w;                 // 0..127
  const int cs_idx = tile & 1, ms = tile >> 1;
  const int lr = lane & 15, lq = lane >> 4;
  const int fo = lq*128 + lr*8;
  const int kc0 = s*8;

  const bf16* Ab = G2 + ((long)(ms*512 + lq)*32 + lr)*8;
  const bf16* tb = w2t2 + (long)cs_idx*130*2048 + fo;

  f32x4 acc[2][4];
  #pragma unroll
  for (int mi=0; mi<2; ++mi)
    #pragma unroll
    for (int ni=0; ni<4; ++ni) acc[mi][ni] = {0.f,0.f,0.f,0.f};

  bf16x8 A[2][2], B[2][4];
  #pragma unroll
  for (int mi=0; mi<2; ++mi)
    A[0][mi] = *(const bf16x8*)(Ab + (long)kc0*1024 + mi*128);
  #pragma unroll
  for (int ni=0; ni<4; ++ni)
    B[0][ni] = *(const bf16x8*)(tb + (long)kc0*2048 + ni*512);

  for (int jj = 0; jj < 4; ++jj) {
    STEPG(0, 1, kc0 + 2*jj + 1);
    STEPG(1, 0, kc0 + 2*jj + 2);
  }

  #pragma unroll
  for (int mi=0; mi<2; ++mi)
    #pragma unroll
    for (int ni=0; ni<4; ++ni) {
      int h = cs_idx*64 + ni*16 + lr;
      #pragma unroll
      for (int r=0; r<4; ++r) {
        int b = ms*32 + mi*16 + lq*4 + r;
        atomicAdd(&out[b*256 + 128 + h], acc[mi][ni][r]);
      }
    }
}

// ---------------- launch ----------------
extern "C" void kernel_launch(void* const* d_in, const int* in_sizes, int n_in,
                              void* d_out, int out_size, void* d_ws, size_t ws_size,
                              hipStream_t stream) {
  const float* in = (const float*)d_in[0];
  const float* W1 = (const float*)d_in[1];
  const float* b1 = (const float*)d_in[2];
  const float* W2 = (const float*)d_in[3];
  const float* b2 = (const float*)d_in[4];
  float* out = (float*)d_out;

  char* ws = (char*)d_ws;
  bf16* w1t  = (bf16*)(ws);                 // 2*27*2048*2  = 221,184
  bf16* w2t2 = (bf16*)(ws + 1048576);       // 2*130*2048*2 = 1,064,960
  bf16* G2   = (bf16*)(ws + 4194304);       // 2048*4096*2  = 16,777,216 (end ~21 MB)

  prep_all<<<2512, 256, 0, stream>>>(W1, W2, w1t, w2t2);
  cin1G   <<<1024, 256, 0, stream>>>(in, w1t, b1, b2, G2, out);
  gemm2   <<<512,  256, 0, stream>>>(G2, w2t2, out);
}

// Round 15
// 107.357 us; speedup vs baseline: 1.0454x; 1.0454x over previous
//
#include <hip/hip_runtime.h>

typedef __bf16 bf16;
typedef __bf16 bf16x8 __attribute__((ext_vector_type(8)));
typedef __bf16 bf16x4 __attribute__((ext_vector_type(4)));
typedef float f32x4 __attribute__((ext_vector_type(4)));
typedef unsigned int u32;

#define NB    2048
#define NM    26
#define NJP   27      // 26 K-chunks + 1 zero pad (unconditional weight prefetch)

__device__ __forceinline__ void gl_lds16(const bf16* g, bf16* l) {
  __builtin_amdgcn_global_load_lds(
      (const __attribute__((address_space(1))) void*)g,
      (__attribute__((address_space(3))) void*)l, 16, 0, 0);
}

__device__ __forceinline__ bf16x8 splat8(u32 p) {
  union { u32 u[4]; bf16x8 v; } s;
  s.u[0] = p; s.u[1] = p; s.u[2] = p; s.u[3] = p;
  return s.v;
}

__device__ __forceinline__ u32 dup16(float v) {
  union { bf16 h; unsigned short s; } cv; cv.h = (bf16)v;
  return (u32)cv.s * 0x10001u;
}

// ---------------- fused prep: frag-linear weight tiles + out bias init --------
// Weight tiles FRAGMENT-LINEAR: in a 64x32 tile, element (r=ni*16+lr,
// c=lq*8+el) lives at ni*512 + lq*128 + lr*8 + el.
__global__ __launch_bounds__(256) void prep_all(
    const float* __restrict__ W1, const float* __restrict__ W2,
    const float* __restrict__ b2,
    bf16* __restrict__ w1t, bf16* __restrict__ w2t2, float* __restrict__ out)
{
  const int bid = blockIdx.x, t = threadIdx.x;
  if (bid < 432) {                        // w1t tiles [cs(2)][c(NJP)], frag-linear
    int e = bid*256 + t;
    int el = e & 7, lr = (e >> 3) & 15, lq = (e >> 7) & 3, ni = (e >> 9) & 3;
    int rest = e >> 11;
    int c = rest % NJP, cs_idx = rest / NJP;
    int h = cs_idx*64 + ni*16 + lr;
    int i = lq*8 + el;
    float v = (i < NM && c < NM) ? W1[h*(NM*NM) + i*NM + c] : 0.f;
    w1t[e] = (bf16)v;
  } else if (bid < 2512) {                // w2t2 tiles [cs(2)][kc(130)], frag-linear
    int e = (bid-432)*256 + t;            // flatK = kc*32 + c  (kc=i, c=j)
    int el = e & 7, lr = (e >> 3) & 15, lq = (e >> 7) & 3, ni = (e >> 9) & 3;
    int rest = e >> 11;                   // [0, 260)
    int kc = rest % 130, cs_idx = rest / 130;
    int h = cs_idx*64 + ni*16 + lr;
    int c = lq*8 + el;
    float v = (kc < 128 && c < NM) ? W2[h*(128*NM) + kc*NM + c] : 0.f;
    w2t2[e] = (bf16)v;
  } else {                                // out[b][128+h] = 32*b2[h]
    int e = (bid-2512)*256 + t;           // [0, NB*128)
    int b = e >> 7, h = e & 127;
    out[b*256 + 128 + h] = 32.0f * b2[h];
  }
}

// one K-chunk step: barrier; stage chunk J+1 into LDS buf NXT; A-scalars
// prefetched straight from `in` (broadcast 64B run); compute from CUR.
// (R14 note: pairing chunks to halve barriers measured NEUTRAL (110.7->112.2);
// the single-chunk loop is the measured-best shape. Keep.)
#define STEP(CUR, NXT, J) do {                                                 \
  __syncthreads();                                                             \
  gl_lds16(tb + (long)((J)+1)*2048 + t*8, &ldsB[NXT][t*8]);                    \
  { int jn = ((J)+1 > 25) ? 25 : (J)+1;  /* chunk-26 weights are zero */       \
    sc[NXT][0] = dup16(spw[jn*32]);                                            \
    sc[NXT][1] = dup16(spw[jn*32 + 16]); }                                     \
  bf16x8 bfr[4];                                                               \
  _Pragma("unroll")                                                            \
  for (int ni = 0; ni < 4; ++ni)                                               \
    bfr[ni] = *(const bf16x8*)&ldsB[CUR][ni*512 + fo];                         \
  _Pragma("unroll")                                                            \
  for (int mi = 0; mi < 2; ++mi) {                                             \
    bf16x8 af = xf[mi] * splat8(sc[CUR][mi]);                                  \
    _Pragma("unroll")                                                          \
    for (int ni = 0; ni < 4; ++ni)                                             \
      acc[mi][ni] = __builtin_amdgcn_mfma_f32_16x16x32_bf16(af, bfr[ni],       \
                                                            acc[mi][ni], 0, 0, 0); \
  }                                                                            \
} while (0)

// ---------------- layer 1 + fused G: wave = 1 batch (32 rows) x one cs-half ---
// K-loop computes x1 (C-layout acc); epilogue writes out[:,0:128], transposes
// x1 through wave-private LDS into A-layout, and emits G2 in gemm2's tiled
// layout: G2[(ms*512 + k8)*32 + mloc][8], flatK = i*32+j, k8 = flatK>>3.
// NOTE: __launch_bounds__(256, 4) is load-bearing. 5/6 waves/EU makes the
// allocator collapse to 40 VGPRs -> acc spills -> ~90 MB scratch traffic
// (measured R7, R12). Do not raise.
__global__ __launch_bounds__(256, 4) void cin1G(
    const float* __restrict__ in, const bf16* __restrict__ w1t,
    const float* __restrict__ b1, bf16* __restrict__ G2, float* __restrict__ out)
{
  __shared__ __align__(16) bf16 ldsB[2][2048];
  __shared__ __align__(16) bf16 ldsT[4][64*36];   // wave-private x1^T [i64][k32+pad]
  const int t = threadIdx.x;
  const int lane = t & 63, w = t >> 6;
  const int cs_idx = blockIdx.x & 1, cs = cs_idx * 64;
  const int strip = blockIdx.x >> 1;
  const int bw = strip*4 + w;                     // this wave's batch
  const int lr = lane & 15, lq = lane >> 4;
  const int fo = lq*128 + lr*8;

  const float* bin = in + (long)bw*(NM*32);
  const float* spw = bin + lr;                    // + j*32 + mi*16 (k = mi*16+lr)

  // x0 A-frags direct from in: xf[mi][e] = x0[bw][j=lq*8+e][k=mi*16+lr]
  bf16x8 xf[2];
  #pragma unroll
  for (int mi = 0; mi < 2; ++mi)
    #pragma unroll
    for (int e = 0; e < 8; ++e) {
      int j = lq*8 + e;
      xf[mi][e] = (bf16)((j < NM) ? bin[j*32 + mi*16 + lr] : 0.f);
    }

  f32x4 acc[2][4];
  #pragma unroll
  for (int mi=0; mi<2; ++mi)
    #pragma unroll
    for (int ni=0; ni<4; ++ni) acc[mi][ni] = {0.f,0.f,0.f,0.f};

  const bf16* tb = w1t + (long)cs_idx*NJP*2048;

  u32 sc[2][2];
  gl_lds16(tb + t*8, &ldsB[0][t*8]);              // stage chunk 0
  sc[0][0] = dup16(spw[0]);  sc[0][1] = dup16(spw[16]);

  for (int jj = 0; jj < 13; ++jj) {
    STEP(0, 1, 2*jj);
    STEP(1, 0, 2*jj + 1);
  }

  float bias[4];
  #pragma unroll
  for (int ni=0; ni<4; ++ni) bias[ni] = b1[cs + ni*16 + lr];

  // out[bw][0:128] = k-sum of x1 + 32*bias
  #pragma unroll
  for (int ni=0; ni<4; ++ni) {
    float v = 0.f;
    #pragma unroll
    for (int mi=0; mi<2; ++mi)
      #pragma unroll
      for (int r=0; r<4; ++r) v += acc[mi][ni][r];
    v += __shfl_xor(v, 16, 64);
    v += __shfl_xor(v, 32, 64);
    if (lq == 0) out[bw*256 + cs + ni*16 + lr] = v + 32.0f * bias[ni];
  }

  // x1 (C-layout) -> wave-private LDS [i_local][k], row stride 36
  bf16* T = &ldsT[w][0];
  #pragma unroll
  for (int mi=0; mi<2; ++mi)
    #pragma unroll
    for (int ni=0; ni<4; ++ni) {
      bf16x4 pk;
      #pragma unroll
      for (int r=0; r<4; ++r) pk[r] = (bf16)(acc[mi][ni][r] + bias[ni]);
      *(bf16x4*)&T[(ni*16+lr)*36 + mi*16 + lq*4] = pk;
    }
  // no barrier: each wave reads only its own tile (lgkmcnt ordering)

  // B-frags: x0[j][k] from in
  bf16x8 bg[2];
  #pragma unroll
  for (int nt = 0; nt < 2; ++nt) {
    int j = nt*16 + lr;
    bf16x8 v;
    #pragma unroll
    for (int e=0; e<8; ++e) v[e] = (bf16)0.f;
    if (j < NM) {
      const float* src = bin + j*32 + lq*8;
      f32x4 a = *(const f32x4*)src, c = *(const f32x4*)(src+4);
      #pragma unroll
      for (int e=0; e<4; ++e) { v[e] = (bf16)a[e]; v[4+e] = (bf16)c[e]; }
    }
    bg[nt] = v;
  }
  // G-MFMAs + tiled G2 stores
  const long gbase = (long)(bw >> 5)*131072 + (bw & 31)*8;
  #pragma unroll
  for (int mt = 0; mt < 4; ++mt) {
    bf16x8 ag = *(const bf16x8*)&T[(mt*16+lr)*36 + lq*8];
    #pragma unroll
    for (int nt = 0; nt < 2; ++nt) {
      f32x4 z = {0.f,0.f,0.f,0.f};
      f32x4 g = __builtin_amdgcn_mfma_f32_16x16x32_bf16(ag, bg[nt], z, 0, 0, 0);
      const int jh = nt*2 + (lr >> 3), jl = lr & 7;
      #pragma unroll
      for (int r = 0; r < 4; ++r) {
        int i = cs + mt*16 + lq*4 + r;
        G2[gbase + (long)(i*4 + jh)*256 + jl] = (bf16)g[r];
      }
    }
  }
}

// ---------------- gemm2: out[b][128+h] += sum_K G[b][K]*W2p[h][K] -------------
// M=2048 b (tiles of 32), N=128 h, K=4096 flat; split-K x8; atomics into out.
#define STEPG(CUR, NXT, KN) do {                                               \
  _Pragma("unroll")                                                            \
  for (int mi = 0; mi < 2; ++mi)                                               \
    A[NXT][mi] = *(const bf16x8*)(Ab + (long)(KN)*1024 + mi*128);              \
  _Pragma("unroll")                                                            \
  for (int ni = 0; ni < 4; ++ni)                                               \
    B[NXT][ni] = *(const bf16x8*)(tb + (long)(KN)*2048 + ni*512);              \
  _Pragma("unroll")                                                            \
  for (int mi = 0; mi < 2; ++mi)                                               \
    _Pragma("unroll")                                                          \
    for (int ni = 0; ni < 4; ++ni)                                             \
      acc[mi][ni] = __builtin_amdgcn_mfma_f32_16x16x32_bf16(A[CUR][mi],        \
                                  B[CUR][ni], acc[mi][ni], 0, 0, 0);           \
} while (0)

__global__ __launch_bounds__(256, 4) void gemm2(
    const bf16* __restrict__ G2, const bf16* __restrict__ w2t2, float* __restrict__ out)
{
  const int t = threadIdx.x;
  const int lane = t & 63, w = t >> 6;
  const int s = blockIdx.x >> 5;              // 8 splits
  const int q32 = blockIdx.x & 31;
  const int tile = q32*4 + w;                 // 0..127
  const int cs_idx = tile & 1, ms = tile >> 1;
  const int lr = lane & 15, lq = lane >> 4;
  const int fo = lq*128 + lr*8;
  const int kc0 = s*16;

  const bf16* Ab = G2 + ((long)(ms*512 + lq)*32 + lr)*8;
  const bf16* tb = w2t2 + (long)cs_idx*130*2048 + fo;

  f32x4 acc[2][4];
  #pragma unroll
  for (int mi=0; mi<2; ++mi)
    #pragma unroll
    for (int ni=0; ni<4; ++ni) acc[mi][ni] = {0.f,0.f,0.f,0.f};

  bf16x8 A[2][2], B[2][4];
  #pragma unroll
  for (int mi=0; mi<2; ++mi)
    A[0][mi] = *(const bf16x8*)(Ab + (long)kc0*1024 + mi*128);
  #pragma unroll
  for (int ni=0; ni<4; ++ni)
    B[0][ni] = *(const bf16x8*)(tb + (long)kc0*2048 + ni*512);

  for (int jj = 0; jj < 8; ++jj) {
    STEPG(0, 1, kc0 + 2*jj + 1);
    STEPG(1, 0, kc0 + 2*jj + 2);
  }

  #pragma unroll
  for (int mi=0; mi<2; ++mi)
    #pragma unroll
    for (int ni=0; ni<4; ++ni) {
      int h = cs_idx*64 + ni*16 + lr;
      #pragma unroll
      for (int r=0; r<4; ++r) {
        int b = ms*32 + mi*16 + lq*4 + r;
        atomicAdd(&out[b*256 + 128 + h], acc[mi][ni][r]);
      }
    }
}

// ---------------- launch ----------------
extern "C" void kernel_launch(void* const* d_in, const int* in_sizes, int n_in,
                              void* d_out, int out_size, void* d_ws, size_t ws_size,
                              hipStream_t stream) {
  const float* in = (const float*)d_in[0];
  const float* W1 = (const float*)d_in[1];
  const float* b1 = (const float*)d_in[2];
  const float* W2 = (const float*)d_in[3];
  const float* b2 = (const float*)d_in[4];
  float* out = (float*)d_out;

  char* ws = (char*)d_ws;
  bf16* w1t  = (bf16*)(ws);                 // 2*27*2048*2  = 221,184
  bf16* w2t2 = (bf16*)(ws + 1048576);       // 2*130*2048*2 = 1,064,960
  bf16* G2   = (bf16*)(ws + 4194304);       // 2048*4096*2  = 16,777,216 (end ~21 MB)

  prep_all<<<3536, 256, 0, stream>>>(W1, W2, b2, w1t, w2t2, out);
  cin1G   <<<1024, 256, 0, stream>>>(in, w1t, b1, G2, out);
  gemm2   <<<256,  256, 0, stream>>>(G2, w2t2, out);
}